// Round 9
// baseline (225.110 us; speedup 1.0000x reference)
//
#include <hip/hip_runtime.h>
#include <math.h>

typedef __bf16 bf16_t;
typedef __bf16 bfrag8 __attribute__((ext_vector_type(8)));
typedef float  facc4  __attribute__((ext_vector_type(4)));
typedef float  f32x2  __attribute__((ext_vector_type(2)));

#define NBUCK 512   // dst-buckets for CSR multisplit (requires N < 65536 for 16-bit packing)
#define BCAP  4096  // per-bucket ebuf capacity (mean 1568, sd ~40)
#define BINCH 2048  // edges per bin2 block
#define KN 4        // nodes per wave in k_agg_p (interleaved gather chains)

__device__ inline unsigned short f2b(float x) {          // RNE float->bf16 bits
    unsigned int u = __float_as_uint(x);
    unsigned int r = (u + 0x7fffu + ((u >> 16) & 1u)) >> 16;
    return (unsigned short)r;
}
__device__ inline unsigned int pack2(float lo, float hi) {
    return (unsigned int)f2b(lo) | ((unsigned int)f2b(hi) << 16);
}
__device__ inline float blo(unsigned int q) { return __uint_as_float(q << 16); }
__device__ inline float bhi(unsigned int q) { return __uint_as_float(q & 0xffff0000u); }

// ---- fp8 e4m3 (OCP) encode/decode: HW cvt path with portable fallback ----
#if __has_builtin(__builtin_amdgcn_cvt_pk_f32_fp8) && __has_builtin(__builtin_amdgcn_cvt_pk_fp8_f32)
#define HW_FP8 1
#endif

__device__ inline f32x2 fp8pair_dec(unsigned short v) {
#ifdef HW_FP8
    return __builtin_amdgcn_cvt_pk_f32_fp8((int)(unsigned int)v, false);
#else
    f32x2 r;
    unsigned char b0 = (unsigned char)(v & 0xff), b1 = (unsigned char)(v >> 8);
    {
        int e = (b0 >> 3) & 0xf, m = b0 & 7;
        float mag = e ? ldexpf(8.f + m, e - 10) : ldexpf((float)m, -9);
        r.x = (b0 & 0x80) ? -mag : mag;
    }
    {
        int e = (b1 >> 3) & 0xf, m = b1 & 7;
        float mag = e ? ldexpf(8.f + m, e - 10) : ldexpf((float)m, -9);
        r.y = (b1 & 0x80) ? -mag : mag;
    }
    return r;
#endif
}
__device__ inline unsigned char fp8_enc(float x) {
#ifdef HW_FP8
    return (unsigned char)(__builtin_amdgcn_cvt_pk_fp8_f32(x, x, 0, false) & 0xff);
#else
    unsigned char s = (x < 0.f) ? 0x80 : 0;
    float ax = fabsf(x);
    if (!(ax > 0.f)) return s;
    if (ax >= 448.f) return s | 0x7e;
    if (ax < 0.015625f) {
        int q = (int)rintf(ax * 512.f);
        return s | (unsigned char)q;
    }
    int e; float m = frexpf(ax, &e);
    int q = (int)rintf(m * 16.f);
    int E = e - 1;
    if (q == 16) { q = 8; ++E; }
    if (E > 8) return s | 0x7e;
    return s | (unsigned char)(((E + 7) << 3) | (q - 8));
#endif
}

__device__ inline int bucket_of(int d, int N) {
    return (int)(((long long)d * NBUCK) / N);
}

// ======================================================================
// Shared-memory overlay bodies. All bodies run with 256 threads and take
// a raw LDS arena (34816 B -> 4 blocks/CU) so kernels share one dispatch.
// ======================================================================

// ---------------- CSR build, pass 1: LDS multisplit into per-bucket ebuf regions.
// BINCH=2048 edges/block, 8 per thread.  LDS use: 23552 B.
__device__ inline void bin2_body(char* smem, const int* __restrict__ src,
                                 const int* __restrict__ dst,
                                 int* __restrict__ bcnt,
                                 unsigned int* __restrict__ ebuf,
                                 int E, int N, int bb) {
    unsigned int* sorted = (unsigned int*)smem;          // 2048 u32 (8192 B)
    int* hist   = (int*)(smem + 16384);                  // 512 int
    int* lstart = (int*)(smem + 18432);                  // 512 int
    int* gbase  = (int*)(smem + 20480);                  // 512 int
    int* sm     = (int*)(smem + 22528);                  // 256 int
    int tid = threadIdx.x;
    int base = bb * BINCH;
    int cnt = min(BINCH, E - base);
    hist[tid] = 0; hist[tid + 256] = 0;
    __syncthreads();
    unsigned int mye[8]; int myb[8];
#pragma unroll
    for (int i = 0; i < 8; ++i) {
        int idx = i * 256 + tid;
        myb[i] = -1;
        if (idx < cnt) {
            int e = base + idx;
            int s = src[e], d = dst[e];
            mye[i] = ((unsigned int)s << 16) | (unsigned int)d;   // needs s,d < 65536
            int b = bucket_of(d, N);
            myb[i] = b;
            atomicAdd(&hist[b], 1);
        }
    }
    __syncthreads();
    int p0 = hist[2 * tid], p1 = hist[2 * tid + 1];
    sm[tid] = p0 + p1;
    __syncthreads();
    for (int off = 1; off < 256; off <<= 1) {
        int x = (tid >= off) ? sm[tid - off] : 0;
        __syncthreads();
        sm[tid] += x;
        __syncthreads();
    }
    int excl = sm[tid] - (p0 + p1);
    lstart[2 * tid] = excl;
    lstart[2 * tid + 1] = excl + p0;
    __syncthreads();
    hist[tid] = lstart[tid]; hist[tid + 256] = lstart[tid + 256];
    __syncthreads();
#pragma unroll
    for (int i = 0; i < 8; ++i) {
        if (myb[i] >= 0) {
            int pos = atomicAdd(&hist[myb[i]], 1);
            sorted[pos] = mye[i];
        }
    }
    __syncthreads();
    for (int b = tid; b < NBUCK; b += 256) {
        int c = hist[b] - lstart[b];
        gbase[b] = (c > 0) ? atomicAdd(&bcnt[b], c) : 0;
    }
    __syncthreads();
    for (int idx = tid; idx < cnt; idx += 256) {
        unsigned int v = sorted[idx];
        int b = bucket_of((int)(v & 0xffffu), N);
        ebuf[(size_t)b * BCAP + gbase[b] + (idx - lstart[b])] = v;
    }
}

// ---------------- pass 2: per-bucket CSR build; bucket base via inline reduction.
// LDS use: 10752 B.
__device__ inline void build2_body(char* smem, const unsigned int* __restrict__ ebuf,
                                   const int* __restrict__ bcnt,
                                   int* __restrict__ offs,
                                   float* __restrict__ dinv,
                                   unsigned short* __restrict__ csr,
                                   int N, int E, int b) {
    unsigned short* seg = (unsigned short*)smem;         // 4096 u16 (8192 B)
    int* cnt_l  = (int*)(smem + 8192);                   // 128
    int* scan_l = (int*)(smem + 8704);                   // 128
    int* curs   = (int*)(smem + 9216);                   // 128
    int* smr    = (int*)(smem + 9728);                   // 256
    int tid = threadIdx.x;
    int part = 0;
    for (int j = tid; j < b; j += 256) part += bcnt[j];
    smr[tid] = part;
    __syncthreads();
    for (int off = 128; off > 0; off >>= 1) {
        if (tid < off) smr[tid] += smr[tid + off];
        __syncthreads();
    }
    int base = smr[0];
    int lo = (int)(((long long)b * N + NBUCK - 1) / NBUCK);
    int cnt = bcnt[b];
    int nrange = (int)(((long long)(b + 1) * N + NBUCK - 1) / NBUCK) - lo;   // <= 98
    if (b == 0 && tid == 0) offs[N] = E;
    if (tid < 128) cnt_l[tid] = 0;
    __syncthreads();
    for (int i = tid; i < cnt; i += 256) {
        unsigned int v = ebuf[(size_t)b * BCAP + i];
        atomicAdd(&cnt_l[(int)(v & 0xffffu) - lo], 1);
    }
    __syncthreads();
    if (tid < 128) scan_l[tid] = cnt_l[tid];
    __syncthreads();
    for (int off = 1; off < 128; off <<= 1) {
        int x = 0;
        if (tid < 128 && tid >= off) x = scan_l[tid - off];
        __syncthreads();
        if (tid < 128) scan_l[tid] += x;
        __syncthreads();
    }
    if (tid < 128) {
        int excl = scan_l[tid] - cnt_l[tid];
        curs[tid] = excl;
        if (tid < nrange) {
            offs[lo + tid] = base + excl;
            dinv[lo + tid] = rsqrtf((float)(cnt_l[tid] + 1));   // +1 = self loop
        }
    }
    __syncthreads();
    for (int i = tid; i < cnt; i += 256) {
        unsigned int v = ebuf[(size_t)b * BCAP + i];
        int d = (int)(v & 0xffffu) - lo;
        int p = atomicAdd(&curs[d], 1);
        seg[p] = (unsigned short)(v >> 16);
    }
    __syncthreads();
    for (int i = tid; i < cnt; i += 256) csr[base + i] = seg[i];
}

// ---------------- gemm1 tile (fp32 A, inline cvt, UNSCALED): out8 = fp8(A @ Bt^T)
// B staged in two 64-row halves -> LDS arena only 34816 B (4 blocks/CU).
// Per-acc MFMA order identical to the full-B version (pure reordering).
__device__ inline void gemm1_body(char* smem, const float* __restrict__ A,
                                  const bf16_t* __restrict__ Bt,
                                  unsigned char* __restrict__ out8, int M, int bb) {
    bf16_t* As = (bf16_t*)smem;                 // 64*136*2 = 17408 B
    bf16_t* Bs = (bf16_t*)(smem + 17408);       // 64*136*2 = 17408 B
    int t = threadIdx.x;
    int wave = t >> 6, lane = t & 63, quad = lane >> 4, l16 = lane & 15;
    int r0 = bb * 64;
#pragma unroll
    for (int i = 0; i < 4; ++i) {
        int chunk = t + i * 256;
        int row = chunk >> 4, c8 = (chunk & 15) << 3;
        int gr = r0 + row;
        float4 a0 = make_float4(0.f, 0.f, 0.f, 0.f), a1 = a0;
        if (gr < M) {
            a0 = *(const float4*)&A[(size_t)gr * 128 + c8];
            a1 = *(const float4*)&A[(size_t)gr * 128 + c8 + 4];
        }
        *(uint4*)&As[row * 136 + c8] =
            make_uint4(pack2(a0.x, a0.y), pack2(a0.z, a0.w),
                       pack2(a1.x, a1.y), pack2(a1.z, a1.w));
    }
    facc4 acc[8];
#pragma unroll
    for (int nt = 0; nt < 8; ++nt) acc[nt] = (facc4){0.f, 0.f, 0.f, 0.f};
    int arow = (wave << 4) + l16;
#pragma unroll
    for (int h = 0; h < 2; ++h) {
#pragma unroll
        for (int i = 0; i < 4; ++i) {
            int chunk = t + i * 256;
            int row = chunk >> 4, c8 = (chunk & 15) << 3;
            *(uint4*)&Bs[row * 136 + c8] = *(const uint4*)&Bt[(h * 64 + row) * 128 + c8];
        }
        __syncthreads();
#pragma unroll
        for (int ks = 0; ks < 4; ++ks) {
            int kk = ks * 32 + quad * 8;
            bfrag8 af = *(const bfrag8*)&As[arow * 136 + kk];
#pragma unroll
            for (int nt = 0; nt < 4; ++nt) {
                bfrag8 bf = *(const bfrag8*)&Bs[(nt * 16 + l16) * 136 + kk];
                acc[h * 4 + nt] = __builtin_amdgcn_mfma_f32_16x16x32_bf16(af, bf, acc[h * 4 + nt], 0, 0, 0);
            }
        }
        __syncthreads();
    }
    unsigned char* f8t = (unsigned char*)As;   // As dead after MFMA
    int wrow0 = (wave << 4) + quad * 4;
#pragma unroll
    for (int r = 0; r < 4; ++r) {
        int row = wrow0 + r;
#pragma unroll
        for (int nt2 = 0; nt2 < 8; ++nt2)
            f8t[row * 128 + (nt2 >> 2) * 64 + (nt2 & 3) * 16 + l16] = fp8_enc(acc[nt2][r]);
    }
    __syncthreads();
#pragma unroll
    for (int i = 0; i < 2; ++i) {
        int idx = t + i * 256;              // 512 chunks of 16B
        int row = idx >> 3, cc = (idx & 7) << 4;
        int gr = r0 + row;
        if (gr < M) *(uint4*)&out8[(size_t)gr * 128 + cc] = *(const uint4*)&f8t[row * 128 + cc];
    }
}

// ---------------- merged dispatches: CSR build || gemm1 halves ----------------
__global__ __launch_bounds__(256) void k_bin_gemm(const int* __restrict__ src,
                                                  const int* __restrict__ dst,
                                                  int* __restrict__ bcnt,
                                                  unsigned int* __restrict__ ebuf,
                                                  int E, int N,
                                                  const float* __restrict__ A,
                                                  const bf16_t* __restrict__ Bt,
                                                  unsigned char* __restrict__ out8,
                                                  int nbin) {
    __shared__ __align__(16) char smem[34816];
    if ((int)blockIdx.x < nbin)
        bin2_body(smem, src, dst, bcnt, ebuf, E, N, blockIdx.x);
    else
        gemm1_body(smem, A, Bt, out8, N, blockIdx.x - nbin);
}

__global__ __launch_bounds__(256) void k_build_gemm(const unsigned int* __restrict__ ebuf,
                                                    const int* __restrict__ bcnt,
                                                    int* __restrict__ offs,
                                                    float* __restrict__ dinv,
                                                    unsigned short* __restrict__ csr,
                                                    int N, int E,
                                                    const float* __restrict__ A,
                                                    const bf16_t* __restrict__ Bt,
                                                    unsigned char* __restrict__ out8,
                                                    int tile0) {
    __shared__ __align__(16) char smem[34816];
    if ((int)blockIdx.x < NBUCK)
        build2_body(smem, ebuf, bcnt, offs, dinv, csr, N, E, blockIdx.x);
    else
        gemm1_body(smem, A, Bt, out8, N, blockIdx.x - NBUCK + tile0);
}

// ---------------- fused prep: bert cvt + W1/W2 transpose + fc1w tiled transpose
//                  + bcnt/logacc zeroing (one graph node) ----------------
__global__ __launch_bounds__(256) void k_prep(const float* __restrict__ bert,
                                              unsigned int* __restrict__ bertb, int n8,
                                              const float* __restrict__ W1,
                                              unsigned short* __restrict__ w1t,
                                              const float* __restrict__ W2,
                                              unsigned short* __restrict__ w2t,
                                              const float* __restrict__ Wf,
                                              unsigned short* __restrict__ fwt,
                                              int* __restrict__ bcnt,
                                              float* __restrict__ logacc) {
    __shared__ float tile[64][65];
    int ncvt = (n8 + 255) / 256;                   // 1536 blocks
    int bb = blockIdx.x, tid = threadIdx.x;
    if (bb < ncvt) {                               // bert fp32 -> bf16
        int i = bb * 256 + tid;
        if (i >= n8) return;
        const float4* p = (const float4*)bert + (size_t)i * 2;
        float4 a = p[0], b = p[1];
        uint4 o;
        o.x = pack2(a.x, a.y);
        o.y = pack2(a.z, a.w);
        o.z = pack2(b.x, b.y);
        o.w = pack2(b.z, b.w);
        ((uint4*)bertb)[i] = o;
        return;
    }
    bb -= ncvt;
    if (bb < 128) {                                // W1/W2 transpose (64KB each)
        int i = bb * 256 + tid;
        const float* W = (i < 16384) ? W1 : W2;
        unsigned short* Wt = (i < 16384) ? w1t : w2t;
        int idx = i & 16383;
        int n = idx >> 7, k = idx & 127;
        Wt[idx] = f2b(W[k * 128 + n]);
        return;
    }
    bb -= 128;
    if (bb < 98) {                                 // fc1w tiled transpose, 7 x 14
        int n0 = (bb % 7) * 64, k0 = (bb / 7) * 64;
#pragma unroll
        for (int i = 0; i < 16; ++i) {
            int idx = i * 256 + tid;
            int r = idx >> 6, c = idx & 63;
            tile[r][c] = Wf[(size_t)(k0 + r) * 448 + n0 + c];
        }
        __syncthreads();
#pragma unroll
        for (int i = 0; i < 16; ++i) {
            int idx = i * 256 + tid;
            int c = idx >> 6, r = idx & 63;
            fwt[(size_t)(n0 + c) * 896 + k0 + r] = f2b(tile[r][c]);
        }
        return;
    }
    // last block: zero bcnt (512) + logacc (4096)
    if (tid < 256) { bcnt[tid] = 0; bcnt[tid + 256] = 0; }
#pragma unroll
    for (int i = 0; i < 16; ++i) logacc[i * 256 + tid] = 0.f;
}

// ---------------- prescale: g8 <- fp8(dec(g8) * dinv[row]) in place ----------------
__global__ __launch_bounds__(256) void k_scale8(unsigned int* __restrict__ g8, // [N][32] u32
                                                const float* __restrict__ dinv, int N) {
    int i = blockIdx.x * 256 + threadIdx.x;      // uint4 index: 16 fp8 per thread
    int total = N * 8;                           // 8 uint4 per 128-fp8 row
    if (i >= total) return;
    int row = i >> 3;
    float d = dinv[row];
    uint4 v = ((const uint4*)g8)[i];
    unsigned int w[4] = {v.x, v.y, v.z, v.w};
#pragma unroll
    for (int q = 0; q < 4; ++q) {
        unsigned int x = w[q], y = 0;
#pragma unroll
        for (int h = 0; h < 2; ++h) {
            f32x2 p = fp8pair_dec((unsigned short)(x >> (h * 16)));
            y |= (unsigned int)fp8_enc(p.x * d) << (h * 16);
            y |= (unsigned int)fp8_enc(p.y * d) << (h * 16 + 8);
        }
        w[q] = y;
    }
    ((uint4*)g8)[i] = make_uint4(w[0], w[1], w[2], w[3]);
}

// ---------------- MFMA GEMM (bf16 A): out8 = fp8((A @ Bt^T) * rs) ----------------
// B staged in two 64-row halves: 34816 B LDS -> 4 blocks/CU.
__global__ __launch_bounds__(256) void k_gemm_nn128(const bf16_t* __restrict__ A,
                                                    const bf16_t* __restrict__ Bt,
                                                    const float* __restrict__ rs,
                                                    unsigned char* __restrict__ out8, int M) {
    __shared__ bf16_t As[64 * 136];
    __shared__ bf16_t Bs[64 * 136];
    int t = threadIdx.x;
    int wave = t >> 6, lane = t & 63, quad = lane >> 4, l16 = lane & 15;
    int r0 = blockIdx.x * 64;
#pragma unroll
    for (int i = 0; i < 4; ++i) {
        int chunk = t + i * 256;
        int row = chunk >> 4, c8 = (chunk & 15) << 3;
        int gr = r0 + row;
        uint4 v = make_uint4(0u, 0u, 0u, 0u);
        if (gr < M) v = *(const uint4*)&A[(size_t)gr * 128 + c8];
        *(uint4*)&As[row * 136 + c8] = v;
    }
    facc4 acc[8];
#pragma unroll
    for (int nt = 0; nt < 8; ++nt) acc[nt] = (facc4){0.f, 0.f, 0.f, 0.f};
    int arow = (wave << 4) + l16;
#pragma unroll
    for (int h = 0; h < 2; ++h) {
#pragma unroll
        for (int i = 0; i < 4; ++i) {
            int chunk = t + i * 256;
            int row = chunk >> 4, c8 = (chunk & 15) << 3;
            *(uint4*)&Bs[row * 136 + c8] = *(const uint4*)&Bt[(h * 64 + row) * 128 + c8];
        }
        __syncthreads();
#pragma unroll
        for (int ks = 0; ks < 4; ++ks) {
            int kk = ks * 32 + quad * 8;
            bfrag8 af = *(const bfrag8*)&As[arow * 136 + kk];
#pragma unroll
            for (int nt = 0; nt < 4; ++nt) {
                bfrag8 bf = *(const bfrag8*)&Bs[(nt * 16 + l16) * 136 + kk];
                acc[h * 4 + nt] = __builtin_amdgcn_mfma_f32_16x16x32_bf16(af, bf, acc[h * 4 + nt], 0, 0, 0);
            }
        }
        __syncthreads();
    }
    unsigned char* f8t = (unsigned char*)As;
    int wrow0 = (wave << 4) + quad * 4;
#pragma unroll
    for (int r = 0; r < 4; ++r) {
        int row = wrow0 + r;
        float sc = rs[min(r0 + row, M - 1)];
#pragma unroll
        for (int nt2 = 0; nt2 < 8; ++nt2)
            f8t[row * 128 + (nt2 >> 2) * 64 + (nt2 & 3) * 16 + l16] = fp8_enc(acc[nt2][r] * sc);
    }
    __syncthreads();
#pragma unroll
    for (int i = 0; i < 2; ++i) {
        int idx = t + i * 256;
        int row = idx >> 3, cc = (idx & 7) << 4;
        int gr = r0 + row;
        if (gr < M) *(uint4*)&out8[(size_t)gr * 128 + cc] = *(const uint4*)&f8t[row * 128 + cc];
    }
}

// ---------------- aggregation: 4 nodes per wave, interleaved gather chains ----------------
// Input rows pre-scaled fp8. Per 8-edge batch, gathers for all KN nodes issue before any
// accumulate (32 loads in flight); block rounds drop ~4x vs wave-per-node.
__global__ __launch_bounds__(256) void k_agg_p(const unsigned short* __restrict__ hx8, // [N][64]
                                               const unsigned short* __restrict__ csr,
                                               const int* __restrict__ offs,
                                               const float* __restrict__ dinv,
                                               const float* __restrict__ bias,
                                               unsigned int* __restrict__ out, int N) {
    int t = threadIdx.x, wv = t >> 6, lane = t & 63;
    int nb = (blockIdx.x * 4 + wv) * KN;          // first node of this wave
    if (nb >= N) return;
    float a0[KN], a1[KN], di[KN];
    int s0[KN], dg[KN];
#pragma unroll
    for (int k = 0; k < KN; ++k) {
        int nd = nb + k;
        if (nd < N) {
            f32x2 s = fp8pair_dec(hx8[(size_t)nd * 64 + lane]);
            a0[k] = s.x; a1[k] = s.y;             // self term (already *dinv)
            s0[k] = offs[nd];
            dg[k] = offs[nd + 1] - s0[k];
            di[k] = dinv[nd];
        } else { a0[k] = a1[k] = 0.f; s0[k] = 0; dg[k] = 0; di[k] = 0.f; }
    }
    int maxd = 0;
#pragma unroll
    for (int k = 0; k < KN; ++k) maxd = max(maxd, dg[k]);
    for (int eb = 0; eb < maxd; eb += 64) {
        int en[KN];
#pragma unroll
        for (int k = 0; k < KN; ++k) {
            int nl = dg[k] - eb;
            en[k] = 0;
            if (nl > 0 && lane < nl) en[k] = (int)csr[s0[k] + eb + lane];
        }
        for (int j = 0; j < 64; j += 8) {
            unsigned short g[KN][8];
            bool any = false;
#pragma unroll
            for (int k = 0; k < KN; ++k) {
                int nl = dg[k] - eb; if (nl > 64) nl = 64;
                if (j < nl) {
                    any = true;
#pragma unroll
                    for (int u = 0; u < 8; ++u) {
                        int sid = __shfl(en[k], j + u, 64);
                        g[k][u] = (j + u < nl) ? hx8[(size_t)sid * 64 + lane] : (unsigned short)0;
                    }
                } else {
#pragma unroll
                    for (int u = 0; u < 8; ++u) g[k][u] = 0;
                }
            }
            if (!any) break;
#pragma unroll
            for (int k = 0; k < KN; ++k)
#pragma unroll
                for (int u = 0; u < 8; ++u) {
                    f32x2 d = fp8pair_dec(g[k][u]);
                    a0[k] += d.x; a1[k] += d.y;
                }
        }
    }
    float2 bb = *(const float2*)&bias[lane * 2];
#pragma unroll
    for (int k = 0; k < KN; ++k) {
        int nd = nb + k;
        if (nd < N) {
            float v0 = fmaxf(a0[k] * di[k] + bb.x, 0.f);
            float v1 = fmaxf(a1[k] * di[k] + bb.y, 0.f);
            out[(size_t)nd * 64 + lane] = pack2(v0, v1);
        }
    }
}

// ---------------- entity mean pool (bf16 in/out): wave per row ----------------
__global__ __launch_bounds__(256) void k_pool_b(const unsigned int* __restrict__ h,
                                                const int* __restrict__ ent,
                                                unsigned int* __restrict__ out) {
    int r = blockIdx.x * 4 + (threadIdx.x >> 6);
    int lane = threadIdx.x & 63;
    float a0 = 0.f, a1 = 0.f;
    int cnt = 0;
#pragma unroll
    for (int m = 0; m < 20; ++m) {
        int id = ent[r * 20 + m];
        if (id >= 0) {
            unsigned int q = h[(size_t)id * 64 + lane];
            a0 += blo(q); a1 += bhi(q); cnt++;
        }
    }
    float inv = 1.f / (float)max(cnt, 1);
    out[(size_t)r * 64 + lane] = pack2(a0 * inv, a1 * inv);
}

// ---------------- MLP fc1+fc2 fused (MFMA): logacc[row] += sum_col relu(...)*fc2w
__global__ __launch_bounds__(256) void k_mlp1_mfma(const bf16_t* __restrict__ bertb,
                                                   const bf16_t* __restrict__ gnnb,
                                                   const bf16_t* __restrict__ fwt,  // [448][896]
                                                   const float* __restrict__ fb,
                                                   const float* __restrict__ w2,   // fc2_w [448]
                                                   float* __restrict__ logacc) {
    __shared__ bf16_t As[64 * 136];
    __shared__ bf16_t Bs[64 * 136];
    int t = threadIdx.x;
    int wave = t >> 6, lane = t & 63, quad = lane >> 4, l16 = lane & 15;
    int r0 = blockIdx.x * 64, c0 = blockIdx.y * 64;
    facc4 acc[4];
#pragma unroll
    for (int nt = 0; nt < 4; ++nt) acc[nt] = (facc4){0.f, 0.f, 0.f, 0.f};

    for (int ks = 0; ks < 7; ++ks) {
#pragma unroll
        for (int i = 0; i < 4; ++i) {
            int chunk = t + i * 256;
            int row = chunk >> 4, c8 = (chunk & 15) << 3;
            int gr = r0 + row;
            const bf16_t* srcp = (ks < 6) ? &bertb[(size_t)gr * 768 + ks * 128 + c8]
                                          : &gnnb[(size_t)gr * 128 + c8];
            *(uint4*)&As[row * 136 + c8] = *(const uint4*)srcp;
        }
#pragma unroll
        for (int i = 0; i < 4; ++i) {
            int chunk = t + i * 256;
            int row = chunk >> 4, c8 = (chunk & 15) << 3;
            *(uint4*)&Bs[row * 136 + c8] =
                *(const uint4*)&fwt[(size_t)(c0 + row) * 896 + ks * 128 + c8];
        }
        __syncthreads();
        int arow = (wave << 4) + l16;
#pragma unroll
        for (int sub = 0; sub < 4; ++sub) {
            int kk = sub * 32 + quad * 8;
            bfrag8 af = *(const bfrag8*)&As[arow * 136 + kk];
#pragma unroll
            for (int nt = 0; nt < 4; ++nt) {
                bfrag8 bf = *(const bfrag8*)&Bs[(nt * 16 + l16) * 136 + kk];
                acc[nt] = __builtin_amdgcn_mfma_f32_16x16x32_bf16(af, bf, acc[nt], 0, 0, 0);
            }
        }
        __syncthreads();
    }
    // epilogue: bias+relu, dot with fc2w slice, reduce over the 16 col-lanes
    int rbase = r0 + (wave << 4) + quad * 4;
    float part[4] = {0.f, 0.f, 0.f, 0.f};
#pragma unroll
    for (int nt = 0; nt < 4; ++nt) {
        int col = c0 + nt * 16 + l16;
        float bb = fb[col];
        float ww = w2[col];
#pragma unroll
        for (int r = 0; r < 4; ++r)
            part[r] += fmaxf(acc[nt][r] + bb, 0.f) * ww;
    }
#pragma unroll
    for (int m = 8; m >= 1; m >>= 1) {
#pragma unroll
        for (int r = 0; r < 4; ++r) part[r] += __shfl_xor(part[r], m, 64);
    }
    if (l16 == 0) {
#pragma unroll
        for (int r = 0; r < 4; ++r) atomicAdd(&logacc[rbase + r], part[r]);
    }
}

// ---------------- sigmoid(logacc + b) ----------------
__global__ void k_sig(const float* __restrict__ logacc, const float* __restrict__ b,
                      float* __restrict__ out, int B) {
    int i = blockIdx.x * 256 + threadIdx.x;
    if (i < B) out[i] = 1.f / (1.f + expf(-(logacc[i] + b[0])));
}

extern "C" void kernel_launch(void* const* d_in, const int* in_sizes, int n_in,
                              void* d_out, int out_size, void* d_ws, size_t ws_size,
                              hipStream_t stream) {
    const float* bert = (const float*)d_in[0];
    const float* x    = (const float*)d_in[1];
    const int*   ei   = (const int*)d_in[2];
    const int*   ent  = (const int*)d_in[3];
    const float* W1   = (const float*)d_in[4];
    const float* b1   = (const float*)d_in[5];
    const float* W2   = (const float*)d_in[6];
    const float* b2   = (const float*)d_in[7];
    const float* fc1w = (const float*)d_in[8];
    const float* fc1b = (const float*)d_in[9];
    const float* fc2w = (const float*)d_in[10];
    const float* fc2b = (const float*)d_in[11];
    float* out = (float*)d_out;

    const int N = in_sizes[1] / 128;   // 50000 (< 65536 required for 16-bit packing)
    const int E = in_sizes[2] / 2;     // 800000
    const int B = in_sizes[0] / 768;   // 4096

    const int* srcv = ei;
    const int* dstv = ei + E;

    char* wsp = (char*)d_ws;
    size_t off = 0;
    auto alloc = [&](size_t bytes) -> void* {
        void* p = wsp + off;
        off += (bytes + 255) & ~(size_t)255;
        return p;
    };
    float* dinv   = (float*)alloc((size_t)N * 4);
    int*   offs   = (int*)alloc((size_t)(N + 1) * 4);
    int*   bcnt   = (int*)alloc(NBUCK * 4);
    float* logacc = (float*)alloc((size_t)B * 4);
    unsigned int*   ebuf  = (unsigned int*)alloc((size_t)NBUCK * BCAP * 4);   // 8 MB
    unsigned short* csr16 = (unsigned short*)alloc((size_t)E * 2);
    bf16_t* bertb = (bf16_t*)alloc((size_t)B * 768 * 2);
    bf16_t* w1t   = (bf16_t*)alloc(128 * 128 * 2);
    bf16_t* w2t   = (bf16_t*)alloc(128 * 128 * 2);
    bf16_t* fwt   = (bf16_t*)alloc((size_t)896 * 448 * 2);
    unsigned char* g8a = (unsigned char*)alloc((size_t)N * 128);   // fp8 x@W1 (then pre-scaled)
    unsigned char* g8b = (unsigned char*)alloc((size_t)N * 128);   // fp8 (h1@W2)*dinv
    bf16_t* hbuf  = (bf16_t*)alloc((size_t)N * 128 * 2);           // agg out (bf16)
    bf16_t* gnnb  = (bf16_t*)alloc((size_t)B * 128 * 2);
    (void)ws_size; (void)n_in; (void)out_size;

    int nb8 = B * 768 / 8;
    int ncvt = (nb8 + 255) / 256;
    int nprep = ncvt + 128 + 98 + 1;
    int nbin = (E + BINCH - 1) / BINCH;  // 391
    int gb = (N + 63) / 64;              // 782
    int g1a = gb / 2, g1b = gb - g1a;    // gemm1 split across the two CSR-build nodes

    k_prep<<<nprep, 256, 0, stream>>>(bert, (unsigned int*)bertb, nb8,
                                      W1, (unsigned short*)w1t, W2, (unsigned short*)w2t,
                                      fc1w, (unsigned short*)fwt, bcnt, logacc);
    // CSR pass 1 || first half of gemm1 (x@W1, unscaled -> g8a)
    k_bin_gemm<<<nbin + g1a, 256, 0, stream>>>(srcv, dstv, bcnt, ebuf, E, N,
                                               x, w1t, g8a, nbin);
    // CSR pass 2 || second half of gemm1
    k_build_gemm<<<NBUCK + g1b, 256, 0, stream>>>(ebuf, bcnt, offs, dinv, csr16, N, E,
                                                  x, w1t, g8a, g1a);
    // prescale g8a by dinv[row] (both agg layers consume pre-scaled input)
    k_scale8<<<(N * 8 + 255) / 256, 256, 0, stream>>>((unsigned int*)g8a, dinv, N);
    // layer 1: interleaved 4-node-per-wave agg -> bf16 hbuf
    k_agg_p<<<(N + 4 * KN * 4 - 1) / (4 * KN), 256, 0, stream>>>(
        (const unsigned short*)g8a, csr16, offs, dinv, b1, (unsigned int*)hbuf, N);
    // h1 @ W2, fp8*dinv epilogue -> g8b
    k_gemm_nn128<<<gb, 256, 0, stream>>>(hbuf, w2t, dinv, g8b, N);
    // layer 2: interleaved agg -> bf16 hbuf
    k_agg_p<<<(N + 4 * KN * 4 - 1) / (4 * KN), 256, 0, stream>>>(
        (const unsigned short*)g8b, csr16, offs, dinv, b2, (unsigned int*)hbuf, N);
    k_pool_b<<<B / 4, 256, 0, stream>>>((const unsigned int*)hbuf, ent, (unsigned int*)gnnb);
    k_mlp1_mfma<<<dim3(B / 64, 7), 256, 0, stream>>>(bertb, gnnb, fwt, fc1b, fc2w, logacc);
    k_sig<<<(B + 255) / 256, 256, 0, stream>>>(logacc, fc2b, out, B);
}

// Round 10
// 212.496 us; speedup vs baseline: 1.0594x; 1.0594x over previous
//
#include <hip/hip_runtime.h>
#include <math.h>

typedef __bf16 bf16_t;
typedef __bf16 bfrag8 __attribute__((ext_vector_type(8)));
typedef float  facc4  __attribute__((ext_vector_type(4)));
typedef float  f32x2  __attribute__((ext_vector_type(2)));

#define NBUCK 512   // dst-buckets for CSR multisplit (requires N < 65536 for 16-bit packing)
#define BCAP  4096  // per-bucket ebuf capacity (mean 1568, sd ~40)

__device__ inline unsigned short f2b(float x) {          // RNE float->bf16 bits
    unsigned int u = __float_as_uint(x);
    unsigned int r = (u + 0x7fffu + ((u >> 16) & 1u)) >> 16;
    return (unsigned short)r;
}
__device__ inline unsigned int pack2(float lo, float hi) {
    return (unsigned int)f2b(lo) | ((unsigned int)f2b(hi) << 16);
}
__device__ inline float blo(unsigned int q) { return __uint_as_float(q << 16); }
__device__ inline float bhi(unsigned int q) { return __uint_as_float(q & 0xffff0000u); }

// ---- fp8 e4m3 (OCP) encode/decode: HW cvt path with portable fallback ----
#if __has_builtin(__builtin_amdgcn_cvt_pk_f32_fp8) && __has_builtin(__builtin_amdgcn_cvt_pk_fp8_f32)
#define HW_FP8 1
#endif

__device__ inline f32x2 fp8pair_dec(unsigned short v) {
#ifdef HW_FP8
    return __builtin_amdgcn_cvt_pk_f32_fp8((int)(unsigned int)v, false);
#else
    f32x2 r;
    unsigned char b0 = (unsigned char)(v & 0xff), b1 = (unsigned char)(v >> 8);
    {
        int e = (b0 >> 3) & 0xf, m = b0 & 7;
        float mag = e ? ldexpf(8.f + m, e - 10) : ldexpf((float)m, -9);
        r.x = (b0 & 0x80) ? -mag : mag;
    }
    {
        int e = (b1 >> 3) & 0xf, m = b1 & 7;
        float mag = e ? ldexpf(8.f + m, e - 10) : ldexpf((float)m, -9);
        r.y = (b1 & 0x80) ? -mag : mag;
    }
    return r;
#endif
}
__device__ inline unsigned char fp8_enc(float x) {
#ifdef HW_FP8
    return (unsigned char)(__builtin_amdgcn_cvt_pk_fp8_f32(x, x, 0, false) & 0xff);
#else
    unsigned char s = (x < 0.f) ? 0x80 : 0;
    float ax = fabsf(x);
    if (!(ax > 0.f)) return s;
    if (ax >= 448.f) return s | 0x7e;
    if (ax < 0.015625f) {
        int q = (int)rintf(ax * 512.f);
        return s | (unsigned char)q;
    }
    int e; float m = frexpf(ax, &e);
    int q = (int)rintf(m * 16.f);
    int E = e - 1;
    if (q == 16) { q = 8; ++E; }
    if (E > 8) return s | 0x7e;
    return s | (unsigned char)(((E + 7) << 3) | (q - 8));
#endif
}

__device__ inline int bucket_of(int d, int N) {
    return (int)(((long long)d * NBUCK) / N);
}

// ======================================================================
// Shared-memory overlay bodies. All bodies run with 256 threads and take
// a raw LDS arena (52224 B) so independent kernels can share one dispatch.
// ======================================================================

// ---------------- CSR build, pass 1: LDS multisplit into per-bucket ebuf regions.
__device__ inline void bin2_body(char* smem, const int* __restrict__ src,
                                 const int* __restrict__ dst,
                                 int* __restrict__ bcnt,
                                 unsigned int* __restrict__ ebuf,
                                 int E, int N, int bb) {
    unsigned int* sorted = (unsigned int*)smem;          // 4096 u32  (16384 B)
    int* hist   = (int*)(smem + 16384);                  // 512 int
    int* lstart = (int*)(smem + 18432);                  // 512 int
    int* gbase  = (int*)(smem + 20480);                  // 512 int
    int* sm     = (int*)(smem + 22528);                  // 256 int
    int tid = threadIdx.x;
    int base = bb * 4096;
    int cnt = min(4096, E - base);
    hist[tid] = 0; hist[tid + 256] = 0;
    __syncthreads();
    unsigned int mye[16]; int myb[16];
#pragma unroll
    for (int i = 0; i < 16; ++i) {
        int idx = i * 256 + tid;
        myb[i] = -1;
        if (idx < cnt) {
            int e = base + idx;
            int s = src[e], d = dst[e];
            mye[i] = ((unsigned int)s << 16) | (unsigned int)d;   // needs s,d < 65536
            int b = bucket_of(d, N);
            myb[i] = b;
            atomicAdd(&hist[b], 1);
        }
    }
    __syncthreads();
    int p0 = hist[2 * tid], p1 = hist[2 * tid + 1];
    sm[tid] = p0 + p1;
    __syncthreads();
    for (int off = 1; off < 256; off <<= 1) {
        int x = (tid >= off) ? sm[tid - off] : 0;
        __syncthreads();
        sm[tid] += x;
        __syncthreads();
    }
    int excl = sm[tid] - (p0 + p1);
    lstart[2 * tid] = excl;
    lstart[2 * tid + 1] = excl + p0;
    __syncthreads();
    hist[tid] = lstart[tid]; hist[tid + 256] = lstart[tid + 256];
    __syncthreads();
#pragma unroll
    for (int i = 0; i < 16; ++i) {
        if (myb[i] >= 0) {
            int pos = atomicAdd(&hist[myb[i]], 1);
            sorted[pos] = mye[i];
        }
    }
    __syncthreads();
    for (int b = tid; b < NBUCK; b += 256) {
        int c = hist[b] - lstart[b];
        gbase[b] = (c > 0) ? atomicAdd(&bcnt[b], c) : 0;
    }
    __syncthreads();
    for (int idx = tid; idx < cnt; idx += 256) {
        unsigned int v = sorted[idx];
        int b = bucket_of((int)(v & 0xffffu), N);
        ebuf[(size_t)b * BCAP + gbase[b] + (idx - lstart[b])] = v;
    }
}

// ---------------- pass 2: per-bucket CSR build; bucket base via inline reduction.
__device__ inline void build2_body(char* smem, const unsigned int* __restrict__ ebuf,
                                   const int* __restrict__ bcnt,
                                   int* __restrict__ offs,
                                   float* __restrict__ dinv,
                                   unsigned short* __restrict__ csr,
                                   int N, int E, int b) {
    unsigned short* seg = (unsigned short*)smem;         // 4096 u16 (8192 B)
    int* cnt_l  = (int*)(smem + 8192);                   // 128
    int* scan_l = (int*)(smem + 8704);                   // 128
    int* curs   = (int*)(smem + 9216);                   // 128
    int* smr    = (int*)(smem + 9728);                   // 256
    int tid = threadIdx.x;
    // base = sum bcnt[0..b) (512 values max -> 2 strided loads + LDS reduce)
    int part = 0;
    for (int j = tid; j < b; j += 256) part += bcnt[j];
    smr[tid] = part;
    __syncthreads();
    for (int off = 128; off > 0; off >>= 1) {
        if (tid < off) smr[tid] += smr[tid + off];
        __syncthreads();
    }
    int base = smr[0];
    int lo = (int)(((long long)b * N + NBUCK - 1) / NBUCK);
    int cnt = bcnt[b];
    int nrange = (int)(((long long)(b + 1) * N + NBUCK - 1) / NBUCK) - lo;   // <= 98
    if (b == 0 && tid == 0) offs[N] = E;
    if (tid < 128) cnt_l[tid] = 0;
    __syncthreads();
    for (int i = tid; i < cnt; i += 256) {
        unsigned int v = ebuf[(size_t)b * BCAP + i];
        atomicAdd(&cnt_l[(int)(v & 0xffffu) - lo], 1);
    }
    __syncthreads();
    if (tid < 128) scan_l[tid] = cnt_l[tid];
    __syncthreads();
    for (int off = 1; off < 128; off <<= 1) {
        int x = 0;
        if (tid < 128 && tid >= off) x = scan_l[tid - off];
        __syncthreads();
        if (tid < 128) scan_l[tid] += x;
        __syncthreads();
    }
    if (tid < 128) {
        int excl = scan_l[tid] - cnt_l[tid];
        curs[tid] = excl;
        if (tid < nrange) {
            offs[lo + tid] = base + excl;
            dinv[lo + tid] = rsqrtf((float)(cnt_l[tid] + 1));   // +1 = self loop
        }
    }
    __syncthreads();
    for (int i = tid; i < cnt; i += 256) {
        unsigned int v = ebuf[(size_t)b * BCAP + i];
        int d = (int)(v & 0xffffu) - lo;
        int p = atomicAdd(&curs[d], 1);
        seg[p] = (unsigned short)(v >> 16);
    }
    __syncthreads();
    for (int i = tid; i < cnt; i += 256) csr[base + i] = seg[i];
}

// ---------------- gemm1 tile (fp32 A, inline cvt, UNSCALED): out8 = fp8(A @ Bt^T)
// dinv[src] deferred into the aggregation so this is CSR-independent.
__device__ inline void gemm1_body(char* smem, const float* __restrict__ A,
                                  const bf16_t* __restrict__ Bt,
                                  unsigned char* __restrict__ out8, int M, int bb) {
    bf16_t* As = (bf16_t*)smem;                 // 64*136*2  = 17408 B
    bf16_t* Bs = (bf16_t*)(smem + 17408);       // 128*136*2 = 34816 B
    int t = threadIdx.x;
    int wave = t >> 6, lane = t & 63, quad = lane >> 4, l16 = lane & 15;
    int r0 = bb * 64;
#pragma unroll
    for (int i = 0; i < 4; ++i) {
        int chunk = t + i * 256;
        int row = chunk >> 4, c8 = (chunk & 15) << 3;
        int gr = r0 + row;
        float4 a0 = make_float4(0.f, 0.f, 0.f, 0.f), a1 = a0;
        if (gr < M) {
            a0 = *(const float4*)&A[(size_t)gr * 128 + c8];
            a1 = *(const float4*)&A[(size_t)gr * 128 + c8 + 4];
        }
        *(uint4*)&As[row * 136 + c8] =
            make_uint4(pack2(a0.x, a0.y), pack2(a0.z, a0.w),
                       pack2(a1.x, a1.y), pack2(a1.z, a1.w));
    }
#pragma unroll
    for (int i = 0; i < 8; ++i) {
        int chunk = t + i * 256;
        int row = chunk >> 4, c8 = (chunk & 15) << 3;
        *(uint4*)&Bs[row * 136 + c8] = *(const uint4*)&Bt[row * 128 + c8];
    }
    __syncthreads();

    facc4 acc[8];
#pragma unroll
    for (int nt = 0; nt < 8; ++nt) acc[nt] = (facc4){0.f, 0.f, 0.f, 0.f};
    int arow = (wave << 4) + l16;
#pragma unroll
    for (int ks = 0; ks < 4; ++ks) {
        int kk = ks * 32 + quad * 8;
        bfrag8 af = *(const bfrag8*)&As[arow * 136 + kk];
#pragma unroll
        for (int nt = 0; nt < 8; ++nt) {
            bfrag8 bf = *(const bfrag8*)&Bs[(nt * 16 + l16) * 136 + kk];
            acc[nt] = __builtin_amdgcn_mfma_f32_16x16x32_bf16(af, bf, acc[nt], 0, 0, 0);
        }
    }
    __syncthreads();
    unsigned char* f8t = (unsigned char*)As;   // 64*128 bytes
    int wrow0 = (wave << 4) + quad * 4;
#pragma unroll
    for (int r = 0; r < 4; ++r) {
        int row = wrow0 + r;
#pragma unroll
        for (int nt = 0; nt < 8; ++nt)
            f8t[row * 128 + nt * 16 + l16] = fp8_enc(acc[nt][r]);
    }
    __syncthreads();
#pragma unroll
    for (int i = 0; i < 2; ++i) {
        int idx = t + i * 256;              // 512 chunks of 16B
        int row = idx >> 3, cc = (idx & 7) << 4;
        int gr = r0 + row;
        if (gr < M) *(uint4*)&out8[(size_t)gr * 128 + cc] = *(const uint4*)&f8t[row * 128 + cc];
    }
}

// ---------------- merged dispatches: CSR build || gemm1 halves ----------------
__global__ __launch_bounds__(256) void k_bin_gemm(const int* __restrict__ src,
                                                  const int* __restrict__ dst,
                                                  int* __restrict__ bcnt,
                                                  unsigned int* __restrict__ ebuf,
                                                  int E, int N,
                                                  const float* __restrict__ A,
                                                  const bf16_t* __restrict__ Bt,
                                                  unsigned char* __restrict__ out8,
                                                  int nbin) {
    __shared__ __align__(16) char smem[52224];
    if ((int)blockIdx.x < nbin)
        bin2_body(smem, src, dst, bcnt, ebuf, E, N, blockIdx.x);
    else
        gemm1_body(smem, A, Bt, out8, N, blockIdx.x - nbin);
}

__global__ __launch_bounds__(256) void k_build_gemm(const unsigned int* __restrict__ ebuf,
                                                    const int* __restrict__ bcnt,
                                                    int* __restrict__ offs,
                                                    float* __restrict__ dinv,
                                                    unsigned short* __restrict__ csr,
                                                    int N, int E,
                                                    const float* __restrict__ A,
                                                    const bf16_t* __restrict__ Bt,
                                                    unsigned char* __restrict__ out8,
                                                    int tile0) {
    __shared__ __align__(16) char smem[52224];
    if ((int)blockIdx.x < NBUCK)
        build2_body(smem, ebuf, bcnt, offs, dinv, csr, N, E, blockIdx.x);
    else
        gemm1_body(smem, A, Bt, out8, N, blockIdx.x - NBUCK + tile0);
}

// ---------------- fused prep: bert cvt + W1/W2 transpose + fc1w tiled transpose
//                  + bcnt/logacc zeroing (one graph node) ----------------
__global__ __launch_bounds__(256) void k_prep(const float* __restrict__ bert,
                                              unsigned int* __restrict__ bertb, int n8,
                                              const float* __restrict__ W1,
                                              unsigned short* __restrict__ w1t,
                                              const float* __restrict__ W2,
                                              unsigned short* __restrict__ w2t,
                                              const float* __restrict__ Wf,
                                              unsigned short* __restrict__ fwt,
                                              int* __restrict__ bcnt,
                                              float* __restrict__ logacc) {
    __shared__ float tile[64][65];
    int ncvt = (n8 + 255) / 256;                   // 1536 blocks
    int bb = blockIdx.x, tid = threadIdx.x;
    if (bb < ncvt) {                               // bert fp32 -> bf16
        int i = bb * 256 + tid;
        if (i >= n8) return;
        const float4* p = (const float4*)bert + (size_t)i * 2;
        float4 a = p[0], b = p[1];
        uint4 o;
        o.x = pack2(a.x, a.y);
        o.y = pack2(a.z, a.w);
        o.z = pack2(b.x, b.y);
        o.w = pack2(b.z, b.w);
        ((uint4*)bertb)[i] = o;
        return;
    }
    bb -= ncvt;
    if (bb < 128) {                                // W1/W2 transpose (64KB each)
        int i = bb * 256 + tid;
        const float* W = (i < 16384) ? W1 : W2;
        unsigned short* Wt = (i < 16384) ? w1t : w2t;
        int idx = i & 16383;
        int n = idx >> 7, k = idx & 127;
        Wt[idx] = f2b(W[k * 128 + n]);
        return;
    }
    bb -= 128;
    if (bb < 98) {                                 // fc1w tiled transpose, 7 x 14
        int n0 = (bb % 7) * 64, k0 = (bb / 7) * 64;
#pragma unroll
        for (int i = 0; i < 16; ++i) {
            int idx = i * 256 + tid;
            int r = idx >> 6, c = idx & 63;
            tile[r][c] = Wf[(size_t)(k0 + r) * 448 + n0 + c];
        }
        __syncthreads();
#pragma unroll
        for (int i = 0; i < 16; ++i) {
            int idx = i * 256 + tid;
            int c = idx >> 6, r = idx & 63;
            fwt[(size_t)(n0 + c) * 896 + k0 + r] = f2b(tile[r][c]);
        }
        return;
    }
    // last block: zero bcnt (512) + logacc (4096)
    if (tid < 256) { bcnt[tid] = 0; bcnt[tid + 256] = 0; }
#pragma unroll
    for (int i = 0; i < 16; ++i) logacc[i * 256 + tid] = 0.f;
}

// ---------------- MFMA GEMM (bf16 A): out8 = fp8((A @ Bt^T) * rs) ----------------
__global__ __launch_bounds__(256) void k_gemm_nn128(const bf16_t* __restrict__ A,
                                                    const bf16_t* __restrict__ Bt,
                                                    const float* __restrict__ rs,
                                                    unsigned char* __restrict__ out8, int M) {
    __shared__ bf16_t As[64 * 136];
    __shared__ bf16_t Bs[128 * 136];
    int t = threadIdx.x;
    int wave = t >> 6, lane = t & 63, quad = lane >> 4, l16 = lane & 15;
    int r0 = blockIdx.x * 64;
#pragma unroll
    for (int i = 0; i < 4; ++i) {
        int chunk = t + i * 256;
        int row = chunk >> 4, c8 = (chunk & 15) << 3;
        int gr = r0 + row;
        uint4 v = make_uint4(0u, 0u, 0u, 0u);
        if (gr < M) v = *(const uint4*)&A[(size_t)gr * 128 + c8];
        *(uint4*)&As[row * 136 + c8] = v;
    }
#pragma unroll
    for (int i = 0; i < 8; ++i) {
        int chunk = t + i * 256;
        int row = chunk >> 4, c8 = (chunk & 15) << 3;
        *(uint4*)&Bs[row * 136 + c8] = *(const uint4*)&Bt[row * 128 + c8];
    }
    __syncthreads();

    facc4 acc[8];
#pragma unroll
    for (int nt = 0; nt < 8; ++nt) acc[nt] = (facc4){0.f, 0.f, 0.f, 0.f};
    int arow = (wave << 4) + l16;
#pragma unroll
    for (int ks = 0; ks < 4; ++ks) {
        int kk = ks * 32 + quad * 8;
        bfrag8 af = *(const bfrag8*)&As[arow * 136 + kk];
#pragma unroll
        for (int nt = 0; nt < 8; ++nt) {
            bfrag8 bf = *(const bfrag8*)&Bs[(nt * 16 + l16) * 136 + kk];
            acc[nt] = __builtin_amdgcn_mfma_f32_16x16x32_bf16(af, bf, acc[nt], 0, 0, 0);
        }
    }
    __syncthreads();
    unsigned char* f8t = (unsigned char*)As;
    int wrow0 = (wave << 4) + quad * 4;
#pragma unroll
    for (int r = 0; r < 4; ++r) {
        int row = wrow0 + r;
        float sc = rs[min(r0 + row, M - 1)];
#pragma unroll
        for (int nt = 0; nt < 8; ++nt)
            f8t[row * 128 + nt * 16 + l16] = fp8_enc(acc[nt][r] * sc);
    }
    __syncthreads();
#pragma unroll
    for (int i = 0; i < 2; ++i) {
        int idx = t + i * 256;
        int row = idx >> 3, cc = (idx & 7) << 4;
        int gr = r0 + row;
        if (gr < M) *(uint4*)&out8[(size_t)gr * 128 + cc] = *(const uint4*)&f8t[row * 128 + cc];
    }
}

// ---------------- agg layer 1: wave per node, per-edge dinv weighting ----------------
// h1[d] = relu(b1 + dinv[d]*(h'[d]*dinv[d] + sum_s h'[s]*dinv[s]))  with h' = g8a (unscaled)
__global__ __launch_bounds__(256) void k_agg_w(const unsigned short* __restrict__ hx8, // [N][64]
                                               const unsigned short* __restrict__ csr,
                                               const int* __restrict__ offs,
                                               const float* __restrict__ dinv,
                                               const float* __restrict__ bias,
                                               unsigned int* __restrict__ out, int N) {
    int node = blockIdx.x * 4 + (threadIdx.x >> 6);
    int lane = threadIdx.x & 63;
    if (node >= N) return;
    float di = dinv[node];
    f32x2 sf = fp8pair_dec(hx8[(size_t)node * 64 + lane]);
    float acc0 = sf.x * di, acc1 = sf.y * di;         // self term: h'[d]*dinv[d]
    int s0 = offs[node], s1 = offs[node + 1];
    for (int base = s0; base < s1; base += 64) {
        int nloc = min(64, s1 - base);
        int en = 0; float dvl = 0.f;
        if (lane < nloc) { en = (int)csr[base + lane]; dvl = dinv[en]; }
        int j = 0;
        for (; j + 16 <= nloc; j += 16) {
            int sid[16]; float dv[16]; unsigned short g[16];
#pragma unroll
            for (int u = 0; u < 16; ++u) {
                sid[u] = __shfl(en, j + u, 64);
                dv[u]  = __shfl(dvl, j + u, 64);
            }
#pragma unroll
            for (int u = 0; u < 16; ++u) g[u] = hx8[(size_t)sid[u] * 64 + lane];  // 16 in flight
#pragma unroll
            for (int u = 0; u < 16; ++u) {
                f32x2 d = fp8pair_dec(g[u]);
                acc0 += d.x * dv[u]; acc1 += d.y * dv[u];
            }
        }
        for (; j + 4 <= nloc; j += 4) {
            int sid[4]; float dv[4]; unsigned short g[4];
#pragma unroll
            for (int u = 0; u < 4; ++u) {
                sid[u] = __shfl(en, j + u, 64);
                dv[u]  = __shfl(dvl, j + u, 64);
            }
#pragma unroll
            for (int u = 0; u < 4; ++u) g[u] = hx8[(size_t)sid[u] * 64 + lane];
#pragma unroll
            for (int u = 0; u < 4; ++u) {
                f32x2 d = fp8pair_dec(g[u]);
                acc0 += d.x * dv[u]; acc1 += d.y * dv[u];
            }
        }
        for (; j < nloc; ++j) {
            int srcn = __shfl(en, j, 64);
            float dv = __shfl(dvl, j, 64);
            f32x2 d = fp8pair_dec(hx8[(size_t)srcn * 64 + lane]);
            acc0 += d.x * dv; acc1 += d.y * dv;
        }
    }
    float2 bb = *(const float2*)&bias[lane * 2];
    float v0 = fmaxf(acc0 * di + bb.x, 0.f);
    float v1 = fmaxf(acc1 * di + bb.y, 0.f);
    out[(size_t)node * 64 + lane] = pack2(v0, v1);
}

// ---------------- agg layer 2: wave per node, fp8 gather (pre-scaled) ----------------
__global__ __launch_bounds__(256) void k_agg_b(const unsigned short* __restrict__ hx8, // [N][64]
                                               const unsigned short* __restrict__ csr,
                                               const int* __restrict__ offs,
                                               const float* __restrict__ dinv,
                                               const float* __restrict__ bias,
                                               unsigned int* __restrict__ out, int N) {
    int node = blockIdx.x * 4 + (threadIdx.x >> 6);
    int lane = threadIdx.x & 63;
    if (node >= N) return;
    float di = dinv[node];
    f32x2 sf = fp8pair_dec(hx8[(size_t)node * 64 + lane]);
    float acc0 = sf.x, acc1 = sf.y;                   // self term (already *dinv)
    int s0 = offs[node], s1 = offs[node + 1];
    for (int base = s0; base < s1; base += 64) {
        int nloc = min(64, s1 - base);
        int en = 0;
        if (lane < nloc) en = (int)csr[base + lane];
        int j = 0;
        for (; j + 16 <= nloc; j += 16) {
            int sid[16]; unsigned short g[16];
#pragma unroll
            for (int u = 0; u < 16; ++u) sid[u] = __shfl(en, j + u, 64);
#pragma unroll
            for (int u = 0; u < 16; ++u) g[u] = hx8[(size_t)sid[u] * 64 + lane];  // 16 in flight
#pragma unroll
            for (int u = 0; u < 16; ++u) { f32x2 d = fp8pair_dec(g[u]); acc0 += d.x; acc1 += d.y; }
        }
        for (; j + 4 <= nloc; j += 4) {
            int sid[4]; unsigned short g[4];
#pragma unroll
            for (int u = 0; u < 4; ++u) sid[u] = __shfl(en, j + u, 64);
#pragma unroll
            for (int u = 0; u < 4; ++u) g[u] = hx8[(size_t)sid[u] * 64 + lane];
#pragma unroll
            for (int u = 0; u < 4; ++u) { f32x2 d = fp8pair_dec(g[u]); acc0 += d.x; acc1 += d.y; }
        }
        for (; j < nloc; ++j) {
            int srcn = __shfl(en, j, 64);
            f32x2 d = fp8pair_dec(hx8[(size_t)srcn * 64 + lane]);
            acc0 += d.x; acc1 += d.y;
        }
    }
    float2 bb = *(const float2*)&bias[lane * 2];
    float v0 = fmaxf(acc0 * di + bb.x, 0.f);
    float v1 = fmaxf(acc1 * di + bb.y, 0.f);
    out[(size_t)node * 64 + lane] = pack2(v0, v1);
}

// ---------------- entity mean pool (bf16 in/out): wave per row ----------------
__global__ __launch_bounds__(256) void k_pool_b(const unsigned int* __restrict__ h,
                                                const int* __restrict__ ent,
                                                unsigned int* __restrict__ out) {
    int r = blockIdx.x * 4 + (threadIdx.x >> 6);
    int lane = threadIdx.x & 63;
    float a0 = 0.f, a1 = 0.f;
    int cnt = 0;
#pragma unroll
    for (int m = 0; m < 20; ++m) {
        int id = ent[r * 20 + m];
        if (id >= 0) {
            unsigned int q = h[(size_t)id * 64 + lane];
            a0 += blo(q); a1 += bhi(q); cnt++;
        }
    }
    float inv = 1.f / (float)max(cnt, 1);
    out[(size_t)r * 64 + lane] = pack2(a0 * inv, a1 * inv);
}

// ---------------- MLP fc1+fc2 fused (MFMA): logacc[row] += sum_col relu(...)*fc2w
__global__ __launch_bounds__(256) void k_mlp1_mfma(const bf16_t* __restrict__ bertb,
                                                   const bf16_t* __restrict__ gnnb,
                                                   const bf16_t* __restrict__ fwt,  // [448][896]
                                                   const float* __restrict__ fb,
                                                   const float* __restrict__ w2,   // fc2_w [448]
                                                   float* __restrict__ logacc) {
    __shared__ bf16_t As[64 * 136];
    __shared__ bf16_t Bs[64 * 136];
    int t = threadIdx.x;
    int wave = t >> 6, lane = t & 63, quad = lane >> 4, l16 = lane & 15;
    int r0 = blockIdx.x * 64, c0 = blockIdx.y * 64;
    facc4 acc[4];
#pragma unroll
    for (int nt = 0; nt < 4; ++nt) acc[nt] = (facc4){0.f, 0.f, 0.f, 0.f};

    for (int ks = 0; ks < 7; ++ks) {
#pragma unroll
        for (int i = 0; i < 4; ++i) {
            int chunk = t + i * 256;
            int row = chunk >> 4, c8 = (chunk & 15) << 3;
            int gr = r0 + row;
            const bf16_t* srcp = (ks < 6) ? &bertb[(size_t)gr * 768 + ks * 128 + c8]
                                          : &gnnb[(size_t)gr * 128 + c8];
            *(uint4*)&As[row * 136 + c8] = *(const uint4*)srcp;
        }
#pragma unroll
        for (int i = 0; i < 4; ++i) {
            int chunk = t + i * 256;
            int row = chunk >> 4, c8 = (chunk & 15) << 3;
            *(uint4*)&Bs[row * 136 + c8] =
                *(const uint4*)&fwt[(size_t)(c0 + row) * 896 + ks * 128 + c8];
        }
        __syncthreads();
        int arow = (wave << 4) + l16;
#pragma unroll
        for (int sub = 0; sub < 4; ++sub) {
            int kk = sub * 32 + quad * 8;
            bfrag8 af = *(const bfrag8*)&As[arow * 136 + kk];
#pragma unroll
            for (int nt = 0; nt < 4; ++nt) {
                bfrag8 bf = *(const bfrag8*)&Bs[(nt * 16 + l16) * 136 + kk];
                acc[nt] = __builtin_amdgcn_mfma_f32_16x16x32_bf16(af, bf, acc[nt], 0, 0, 0);
            }
        }
        __syncthreads();
    }
    // epilogue: bias+relu, dot with fc2w slice, reduce over the 16 col-lanes
    int rbase = r0 + (wave << 4) + quad * 4;
    float part[4] = {0.f, 0.f, 0.f, 0.f};
#pragma unroll
    for (int nt = 0; nt < 4; ++nt) {
        int col = c0 + nt * 16 + l16;
        float bb = fb[col];
        float ww = w2[col];
#pragma unroll
        for (int r = 0; r < 4; ++r)
            part[r] += fmaxf(acc[nt][r] + bb, 0.f) * ww;
    }
#pragma unroll
    for (int m = 8; m >= 1; m >>= 1) {
#pragma unroll
        for (int r = 0; r < 4; ++r) part[r] += __shfl_xor(part[r], m, 64);
    }
    if (l16 == 0) {
#pragma unroll
        for (int r = 0; r < 4; ++r) atomicAdd(&logacc[rbase + r], part[r]);
    }
}

// ---------------- sigmoid(logacc + b) ----------------
__global__ void k_sig(const float* __restrict__ logacc, const float* __restrict__ b,
                      float* __restrict__ out, int B) {
    int i = blockIdx.x * 256 + threadIdx.x;
    if (i < B) out[i] = 1.f / (1.f + expf(-(logacc[i] + b[0])));
}

extern "C" void kernel_launch(void* const* d_in, const int* in_sizes, int n_in,
                              void* d_out, int out_size, void* d_ws, size_t ws_size,
                              hipStream_t stream) {
    const float* bert = (const float*)d_in[0];
    const float* x    = (const float*)d_in[1];
    const int*   ei   = (const int*)d_in[2];
    const int*   ent  = (const int*)d_in[3];
    const float* W1   = (const float*)d_in[4];
    const float* b1   = (const float*)d_in[5];
    const float* W2   = (const float*)d_in[6];
    const float* b2   = (const float*)d_in[7];
    const float* fc1w = (const float*)d_in[8];
    const float* fc1b = (const float*)d_in[9];
    const float* fc2w = (const float*)d_in[10];
    const float* fc2b = (const float*)d_in[11];
    float* out = (float*)d_out;

    const int N = in_sizes[1] / 128;   // 50000 (< 65536 required for 16-bit packing)
    const int E = in_sizes[2] / 2;     // 800000
    const int B = in_sizes[0] / 768;   // 4096

    const int* srcv = ei;
    const int* dstv = ei + E;

    char* wsp = (char*)d_ws;
    size_t off = 0;
    auto alloc = [&](size_t bytes) -> void* {
        void* p = wsp + off;
        off += (bytes + 255) & ~(size_t)255;
        return p;
    };
    float* dinv   = (float*)alloc((size_t)N * 4);
    int*   offs   = (int*)alloc((size_t)(N + 1) * 4);
    int*   bcnt   = (int*)alloc(NBUCK * 4);
    float* logacc = (float*)alloc((size_t)B * 4);
    unsigned int*   ebuf  = (unsigned int*)alloc((size_t)NBUCK * BCAP * 4);   // 8 MB
    unsigned short* csr16 = (unsigned short*)alloc((size_t)E * 2);
    bf16_t* bertb = (bf16_t*)alloc((size_t)B * 768 * 2);
    bf16_t* w1t   = (bf16_t*)alloc(128 * 128 * 2);
    bf16_t* w2t   = (bf16_t*)alloc(128 * 128 * 2);
    bf16_t* fwt   = (bf16_t*)alloc((size_t)896 * 448 * 2);
    unsigned char* g8a = (unsigned char*)alloc((size_t)N * 128);   // fp8 x@W1 (unscaled)
    unsigned char* g8b = (unsigned char*)alloc((size_t)N * 128);   // fp8 (h1@W2)*dinv
    bf16_t* hbuf  = (bf16_t*)alloc((size_t)N * 128 * 2);           // agg out (bf16)
    bf16_t* gnnb  = (bf16_t*)alloc((size_t)B * 128 * 2);
    (void)ws_size; (void)n_in; (void)out_size;

    int nb8 = B * 768 / 8;
    int ncvt = (nb8 + 255) / 256;
    int nprep = ncvt + 128 + 98 + 1;
    int nbin = (E + 4095) / 4096;      // 196
    int gb = (N + 63) / 64;            // 782
    int g1a = gb / 2, g1b = gb - g1a;  // gemm1 split across the two CSR-build nodes

    k_prep<<<nprep, 256, 0, stream>>>(bert, (unsigned int*)bertb, nb8,
                                      W1, (unsigned short*)w1t, W2, (unsigned short*)w2t,
                                      fc1w, (unsigned short*)fwt, bcnt, logacc);
    // CSR pass 1 || first half of gemm1 (x@W1, unscaled -> g8a)
    k_bin_gemm<<<nbin + g1a, 256, 0, stream>>>(srcv, dstv, bcnt, ebuf, E, N,
                                               x, w1t, g8a, nbin);
    // CSR pass 2 || second half of gemm1
    k_build_gemm<<<NBUCK + g1b, 256, 0, stream>>>(ebuf, bcnt, offs, dinv, csr16, N, E,
                                                  x, w1t, g8a, g1a);
    // layer 1: wave-per-node agg with per-edge dinv (unscaled g8a) -> bf16 hbuf
    k_agg_w<<<(N + 3) / 4, 256, 0, stream>>>((const unsigned short*)g8a, csr16, offs, dinv, b1,
                                             (unsigned int*)hbuf, N);
    // h1 @ W2, fp8*dinv epilogue -> g8b
    k_gemm_nn128<<<gb, 256, 0, stream>>>(hbuf, w2t, dinv, g8b, N);
    // layer 2: wave-per-node agg (pre-scaled g8b) -> bf16 hbuf
    k_agg_b<<<(N + 3) / 4, 256, 0, stream>>>((const unsigned short*)g8b, csr16, offs, dinv, b2,
                                             (unsigned int*)hbuf, N);
    k_pool_b<<<B / 4, 256, 0, stream>>>((const unsigned int*)hbuf, ent, (unsigned int*)gnnb);
    k_mlp1_mfma<<<dim3(B / 64, 7), 256, 0, stream>>>(bertb, gnnb, fwt, fc1b, fc2w, logacc);
    k_sig<<<(B + 255) / 256, 256, 0, stream>>>(logacc, fc2b, out, B);
}